// Round 1
// baseline (1210.811 us; speedup 1.0000x reference)
//
#include <hip/hip_runtime.h>
#include <hip/hip_bf16.h>

// Problem constants (from reference):
//   N=8192 nodes, F=128 feats, E=262144 edges/branch, META=64, LAM=16 (out=17)
constexpr int N_ = 8192;
constexpr int F_ = 128;
constexpr int E_ = 262144;
constexpr int OUT_ = 17;   // LAM+1

// ---------------------------------------------------------------------------
// small utility kernels
// ---------------------------------------------------------------------------
__global__ void fill_kernel(float* __restrict__ p, float v, int n) {
    int i = blockIdx.x * blockDim.x + threadIdx.x;
    if (i < n) p[i] = v;
}

__global__ void copy_kernel(float* __restrict__ dst, const float* __restrict__ src, int n) {
    int i = blockIdx.x * blockDim.x + threadIdx.x;
    if (i < n) dst[i] = src[i];
}

// ---------------------------------------------------------------------------
// GCN normalization: deg (incoming, +1 self-loop) and per-edge norm
// ---------------------------------------------------------------------------
__global__ void deg_accum(const int* __restrict__ ei, float* __restrict__ deg, int E) {
    int e = blockIdx.x * blockDim.x + threadIdx.x;
    if (e < E) atomicAdd(&deg[ei[E + e]], 1.0f);   // dst = ei[1][e]
}

__global__ void norm_kernel(const int* __restrict__ ei, const float* __restrict__ deg,
                            float* __restrict__ nrm, int E) {
    int e = blockIdx.x * blockDim.x + threadIdx.x;
    if (e < E) {
        float ds = 1.0f / sqrtf(deg[ei[e]]);       // src
        float dd = 1.0f / sqrtf(deg[ei[E + e]]);   // dst
        nrm[e] = ds * dd;
    }
}

// ---------------------------------------------------------------------------
// Layer 1: h = x @ W1 (128->8), LDS-tiled; also writes self-loop+bias init:
//   out[n][f] = b[f] + h[n][f] / deg[n]
// block = 256 threads handles 32 nodes
// ---------------------------------------------------------------------------
__global__ __launch_bounds__(256) void gcn_l1(
        const float* __restrict__ x, const float* __restrict__ W,
        const float* __restrict__ b, const float* __restrict__ deg,
        float* __restrict__ h, float* __restrict__ out) {
    __shared__ float xs[32][129];   // +1 pad: conflict-free reads below
    __shared__ float Ws[128 * 8];
    int tid = threadIdx.x;
    int n0 = blockIdx.x * 32;

    for (int i = tid; i < 128 * 8; i += 256) Ws[i] = W[i];
    for (int i = tid; i < 32 * 128; i += 256) {
        int nn = i >> 7, ff = i & 127;          // consecutive i -> coalesced
        xs[nn][ff] = x[(size_t)(n0 + nn) * 128 + ff];
    }
    __syncthreads();

    int n = tid >> 3;        // 0..31
    int f = tid & 7;         // 0..7
    float acc = 0.0f;
    #pragma unroll
    for (int k = 0; k < 128; k++) acc += xs[n][k] * Ws[k * 8 + f];

    int node = n0 + n;
    float ds = 1.0f / sqrtf(deg[node]);
    h[node * 8 + f]   = acc;
    out[node * 8 + f] = b[f] + acc * (ds * ds);
}

// ---------------------------------------------------------------------------
// Layers 2-4: small matmul (FIN in {8,4,2}), register-resident, fused with
// self-loop+bias init of the aggregation output.
// ---------------------------------------------------------------------------
template <int FIN, int FOUT>
__global__ __launch_bounds__(256) void gcn_mm(
        const float* __restrict__ x, const float* __restrict__ W,
        const float* __restrict__ b, const float* __restrict__ deg,
        float* __restrict__ h, float* __restrict__ out) {
    int n = blockIdx.x * 256 + threadIdx.x;
    if (n >= N_) return;
    float xi[FIN];
    #pragma unroll
    for (int k = 0; k < FIN; k++) xi[k] = x[n * FIN + k];
    float ds = 1.0f / sqrtf(deg[n]);
    float invdeg = ds * ds;
    #pragma unroll
    for (int f = 0; f < FOUT; f++) {
        float acc = 0.0f;
        #pragma unroll
        for (int k = 0; k < FIN; k++) acc += xi[k] * W[k * FOUT + f];
        h[n * FOUT + f]   = acc;
        out[n * FOUT + f] = b[f] + acc * invdeg;
    }
}

// ---------------------------------------------------------------------------
// Edge aggregation: out[dst] += norm[e] * h[src]   (atomic scatter)
// ---------------------------------------------------------------------------
template <int F>
__global__ __launch_bounds__(256) void gcn_scatter(
        const int* __restrict__ ei, const float* __restrict__ nrm,
        const float* __restrict__ h, float* __restrict__ out, int E) {
    int e = blockIdx.x * 256 + threadIdx.x;
    if (e >= E) return;
    int s = ei[e];
    int d = ei[E + e];
    float nm = nrm[e];
    #pragma unroll
    for (int f = 0; f < F; f++)
        atomicAdd(&out[d * F + f], h[s * F + f] * nm);
}

// ---------------------------------------------------------------------------
// Big GEMV: result[j] += sum_i concat[i] * Wi[i][j]   (Wi is [16384][8192])
// grid = (8 col-strips of 1024, 128 row-chunks of 128); result pre-init to bi.
// Streams all 512 MiB of Wi exactly once, float4-coalesced.
// ---------------------------------------------------------------------------
__global__ __launch_bounds__(256) void gemv_big(
        const float* __restrict__ Wi, const float* __restrict__ c,
        float* __restrict__ out) {
    int col = blockIdx.x * 1024 + threadIdx.x * 4;
    int r0  = blockIdx.y * 128;
    const float* wp = Wi + (size_t)r0 * 8192 + col;
    float4 acc = make_float4(0.f, 0.f, 0.f, 0.f);
    #pragma unroll 4
    for (int i = 0; i < 128; i++) {
        float cv = c[r0 + i];                 // wave-uniform -> scalar load
        float4 w = *reinterpret_cast<const float4*>(wp);
        acc.x += cv * w.x;
        acc.y += cv * w.y;
        acc.z += cv * w.z;
        acc.w += cv * w.w;
        wp += 8192;
    }
    atomicAdd(&out[col + 0], acc.x);
    atomicAdd(&out[col + 1], acc.y);
    atomicAdd(&out[col + 2], acc.z);
    atomicAdd(&out[col + 3], acc.w);
}

// ---------------------------------------------------------------------------
// Final head: out[j] = bf[j] + sum_{i<8256} concat2[i] * Wf[i][j]
// concat2 = [result_inter (8192) ; meta (64)]
// 32 blocks x 258 rows; LDS tree reduce; one atomic per (block, j).
// ---------------------------------------------------------------------------
__global__ void final_init(const float* __restrict__ bf, float* __restrict__ outp) {
    int j = threadIdx.x;
    if (j < OUT_) outp[j] = bf[j];
}

__global__ __launch_bounds__(256) void final_kernel(
        const float* __restrict__ result, const float* __restrict__ meta,
        const float* __restrict__ Wf, float* __restrict__ outp) {
    const int ROWS = 258;                      // 32 * 258 = 8256
    int r0 = blockIdx.x * ROWS;
    float acc[OUT_];
    #pragma unroll
    for (int j = 0; j < OUT_; j++) acc[j] = 0.0f;

    for (int i = r0 + threadIdx.x; i < r0 + ROWS; i += 256) {
        float cv = (i < N_) ? result[i] : meta[i - N_];
        #pragma unroll
        for (int j = 0; j < OUT_; j++) acc[j] += cv * Wf[i * OUT_ + j];
    }

    __shared__ float red[OUT_][257];
    #pragma unroll
    for (int j = 0; j < OUT_; j++) red[j][threadIdx.x] = acc[j];
    __syncthreads();
    for (int s = 128; s > 0; s >>= 1) {
        if (threadIdx.x < s) {
            #pragma unroll
            for (int j = 0; j < OUT_; j++)
                red[j][threadIdx.x] += red[j][threadIdx.x + s];
        }
        __syncthreads();
    }
    if (threadIdx.x == 0) {
        #pragma unroll
        for (int j = 0; j < OUT_; j++) atomicAdd(&outp[j], red[j][0]);
    }
}

// ---------------------------------------------------------------------------
// launcher
// ---------------------------------------------------------------------------
extern "C" void kernel_launch(void* const* d_in, const int* in_sizes, int n_in,
                              void* d_out, int out_size, void* d_ws, size_t ws_size,
                              hipStream_t stream) {
    (void)in_sizes; (void)n_in; (void)out_size; (void)ws_size;

    const float* x1  = (const float*)d_in[0];
    const float* x2  = (const float*)d_in[1];
    const float* meta= (const float*)d_in[2];
    const float* W1  = (const float*)d_in[3];  const float* b1 = (const float*)d_in[4];
    const float* W2  = (const float*)d_in[5];  const float* b2 = (const float*)d_in[6];
    const float* W3  = (const float*)d_in[7];  const float* b3 = (const float*)d_in[8];
    const float* W4  = (const float*)d_in[9];  const float* b4 = (const float*)d_in[10];
    const float* Wi  = (const float*)d_in[11]; const float* bi = (const float*)d_in[12];
    const float* Wf  = (const float*)d_in[13]; const float* bf = (const float*)d_in[14];
    const int*   ei1 = (const int*)d_in[15];
    const int*   ei2 = (const int*)d_in[16];
    float* out = (float*)d_out;

    // workspace layout (floats); ws re-poisoned every call -> init everything used
    float* ws = (float*)d_ws;
    float* deg0   = ws;                    // [N]
    float* deg1   = deg0 + N_;             // [N]
    float* nrm0   = deg1 + N_;             // [E]
    float* nrm1   = nrm0 + E_;             // [E]
    float* ha     = nrm1 + E_;             // [N*8]
    float* hb     = ha + 8 * N_;           // [N*8]
    float* hh     = hb + 8 * N_;           // [N*8]
    float* concat = hh + 8 * N_;           // [2N]
    float* result = concat + 2 * N_;       // [N]

    const int*   eis[2]  = {ei1, ei2};
    const float* xs[2]   = {x1, x2};
    float*       degs[2] = {deg0, deg1};
    float*       nrms[2] = {nrm0, nrm1};

    const int EB = E_ / 256;   // 1024 blocks for edge-parallel kernels
    const int NB = N_ / 256;   // 32 blocks for node-parallel kernels

    for (int br = 0; br < 2; br++) {
        const int* ei = eis[br];
        float* dg = degs[br];
        float* nm = nrms[br];

        fill_kernel<<<NB, 256, 0, stream>>>(dg, 1.0f, N_);          // self-loop
        deg_accum  <<<EB, 256, 0, stream>>>(ei, dg, E_);
        norm_kernel<<<EB, 256, 0, stream>>>(ei, dg, nm, E_);

        // L1: 128 -> 8
        gcn_l1<<<N_ / 32, 256, 0, stream>>>(xs[br], W1, b1, dg, hh, ha);
        gcn_scatter<8><<<EB, 256, 0, stream>>>(ei, nm, hh, ha, E_);
        // L2: 8 -> 4
        gcn_mm<8, 4><<<NB, 256, 0, stream>>>(ha, W2, b2, dg, hh, hb);
        gcn_scatter<4><<<EB, 256, 0, stream>>>(ei, nm, hh, hb, E_);
        // L3: 4 -> 2
        gcn_mm<4, 2><<<NB, 256, 0, stream>>>(hb, W3, b3, dg, hh, ha);
        gcn_scatter<2><<<EB, 256, 0, stream>>>(ei, nm, hh, ha, E_);
        // L4: 2 -> 1, result straight into concat[br*N .. )
        float* bout = concat + br * N_;
        gcn_mm<2, 1><<<NB, 256, 0, stream>>>(ha, W4, b4, dg, hh, bout);
        gcn_scatter<1><<<EB, 256, 0, stream>>>(ei, nm, hh, bout, E_);
    }

    // result_inter = concat @ Wi + bi
    copy_kernel<<<NB, 256, 0, stream>>>(result, bi, N_);
    dim3 gg(8, 128);
    gemv_big<<<gg, 256, 0, stream>>>(Wi, concat, result);

    // out = [result ; meta] @ Wf + bf
    final_init<<<1, 32, 0, stream>>>(bf, out);
    final_kernel<<<32, 256, 0, stream>>>(result, meta, Wf, out);
}

// Round 2
// 940.413 us; speedup vs baseline: 1.2875x; 1.2875x over previous
//
#include <hip/hip_runtime.h>
#include <hip/hip_bf16.h>

// Problem constants: N=8192 nodes, F=128 feats, E=262144 edges/branch,
// META=64, OUT=LAM+1=17.
// KEY ALGEBRA: the GCN branch has NO nonlinearity, so
//   h4 = A^4 X w + A^3 1 b1'W2W3W4 + A^2 1 b2'W3W4 + A 1 b3'W4 + 1 b4
// with w = W1W2W3W4 ([128] vector) and scalar betas. A v is computed as
// dis (*) ((Adj+I)(dis (*) v)) -> 1 GEMV + 4 scalar SpMVs per branch.
constexpr int N_ = 8192;
constexpr int F_ = 128;
constexpr int E_ = 262144;
constexpr int OUT_ = 17;

// ---------------------------------------------------------------------------
// Collapse weights: w[128] = W1@W2@W3@W4 ; betas = {b1'W2W3W4, b2'W3W4, b3'W4, b4}
// ---------------------------------------------------------------------------
__global__ void compute_w(const float* __restrict__ W1, const float* __restrict__ W2,
                          const float* __restrict__ W3, const float* __restrict__ W4,
                          const float* __restrict__ b1, const float* __restrict__ b2,
                          const float* __restrict__ b3, const float* __restrict__ b4,
                          float* __restrict__ w, float* __restrict__ betas) {
    int i = threadIdx.x;  // 128 threads
    float w34[4];
    #pragma unroll
    for (int f = 0; f < 4; f++) w34[f] = W3[f * 2 + 0] * W4[0] + W3[f * 2 + 1] * W4[1];
    float r12[4];
    #pragma unroll
    for (int f = 0; f < 4; f++) {
        float s = 0.f;
        #pragma unroll
        for (int k = 0; k < 8; k++) s += W1[i * 8 + k] * W2[k * 4 + f];
        r12[f] = s;
    }
    float wi = 0.f;
    #pragma unroll
    for (int f = 0; f < 4; f++) wi += r12[f] * w34[f];
    w[i] = wi;
    if (i == 0) {
        float b3W4 = b3[0] * W4[0] + b3[1] * W4[1];
        float b2W34 = 0.f;
        #pragma unroll
        for (int f = 0; f < 4; f++) b2W34 += b2[f] * w34[f];
        float b1W234 = 0.f;
        #pragma unroll
        for (int k = 0; k < 8; k++) {
            float w234k = 0.f;
            #pragma unroll
            for (int f = 0; f < 4; f++) w234k += W2[k * 4 + f] * w34[f];
            b1W234 += b1[k] * w234k;
        }
        betas[0] = b1W234;
        betas[1] = b2W34;
        betas[2] = b3W4;
        betas[3] = b4[0];
    }
}

// ---------------------------------------------------------------------------
// Degree (both branches): deg[2N] init 1.0 (self-loop) + incoming-edge count,
// then dis = 1/sqrt(deg)
// ---------------------------------------------------------------------------
__global__ void deg_fill(float* __restrict__ deg) {
    int i = blockIdx.x * 256 + threadIdx.x;
    if (i < 2 * N_) deg[i] = 1.0f;
}

__global__ void deg_accum2(const int* __restrict__ ei1, const int* __restrict__ ei2,
                           float* __restrict__ deg) {
    int e = blockIdx.x * 256 + threadIdx.x;  // 0..2E
    if (e < E_) atomicAdd(&deg[ei1[E_ + e]], 1.0f);
    else {
        e -= E_;
        atomicAdd(&deg[N_ + ei2[E_ + e]], 1.0f);
    }
}

__global__ void dis_k(const float* __restrict__ deg, float* __restrict__ dis) {
    int i = blockIdx.x * 256 + threadIdx.x;
    if (i < 2 * N_) dis[i] = 1.0f / sqrtf(deg[i]);
}

// ---------------------------------------------------------------------------
// p[b*N+row] = dis * (x_b[row,:] . w) ; also zero q. One wave per row.
// ---------------------------------------------------------------------------
__global__ __launch_bounds__(256) void branch_gemv(
        const float* __restrict__ x1, const float* __restrict__ x2,
        const float* __restrict__ w, const float* __restrict__ dis,
        float* __restrict__ p, float* __restrict__ q) {
    int b = blockIdx.y;
    const float* x = b ? x2 : x1;
    int wave = threadIdx.x >> 6, lane = threadIdx.x & 63;
    int row = blockIdx.x * 4 + wave;
    float2 xv = *reinterpret_cast<const float2*>(x + (size_t)row * F_ + lane * 2);
    float2 wv = *reinterpret_cast<const float2*>(w + lane * 2);
    float s = xv.x * wv.x + xv.y * wv.y;
    #pragma unroll
    for (int o = 32; o > 0; o >>= 1) s += __shfl_down(s, o);
    if (lane == 0) {
        int n = b * N_ + row;
        p[n] = dis[n] * s;
        q[n] = 0.f;
    }
}

// ---------------------------------------------------------------------------
// Scalar SpMV scatter for both branches: q[dst] += p[src]
// ---------------------------------------------------------------------------
__global__ __launch_bounds__(256) void spmv2(const int* __restrict__ ei1,
                                             const int* __restrict__ ei2,
                                             const float* __restrict__ p,
                                             float* __restrict__ q) {
    int e = blockIdx.x * 256 + threadIdx.x;  // 0..2E
    if (e < E_) {
        atomicAdd(&q[ei1[E_ + e]], p[ei1[e]]);
    } else {
        e -= E_;
        atomicAdd(&q[N_ + ei2[E_ + e]], p[N_ + ei2[e]]);
    }
}

// ---------------------------------------------------------------------------
// u = dis*(q+p) + beta ; not-last: p = dis*u, q = 0 ; last: concat = u (+ result=bi)
// ---------------------------------------------------------------------------
template <bool LAST>
__global__ void post2(const float* __restrict__ dis, float* __restrict__ p,
                      float* __restrict__ q, const float* __restrict__ betas, int bidx,
                      float* __restrict__ concat, const float* __restrict__ bi,
                      float* __restrict__ result) {
    int n = blockIdx.x * 256 + threadIdx.x;
    if (n >= 2 * N_) return;
    float u = dis[n] * (q[n] + p[n]) + betas[bidx];
    if (LAST) {
        concat[n] = u;
        if (n < N_) result[n] = bi[n];
    } else {
        p[n] = dis[n] * u;
        q[n] = 0.f;
    }
}

// ---------------------------------------------------------------------------
// Big GEMV: result[j] += sum_i concat[i] * Wi[i][j]  (Wi [16384][8192], 512 MiB)
// grid (8 col-strips, 128 row-chunks); c chunk staged in LDS; 4 atomics/thread.
// ---------------------------------------------------------------------------
__global__ __launch_bounds__(256) void gemv_big(
        const float* __restrict__ Wi, const float* __restrict__ c,
        float* __restrict__ out) {
    __shared__ float cs[128];
    int r0 = blockIdx.y * 128;
    if (threadIdx.x < 128) cs[threadIdx.x] = c[r0 + threadIdx.x];
    __syncthreads();
    int col = blockIdx.x * 1024 + threadIdx.x * 4;
    const float* wp = Wi + (size_t)r0 * 8192 + col;
    float4 acc = make_float4(0.f, 0.f, 0.f, 0.f);
    #pragma unroll 4
    for (int i = 0; i < 128; i++) {
        float cv = cs[i];
        float4 wv = *reinterpret_cast<const float4*>(wp);
        acc.x += cv * wv.x;
        acc.y += cv * wv.y;
        acc.z += cv * wv.z;
        acc.w += cv * wv.w;
        wp += 8192;
    }
    atomicAdd(&out[col + 0], acc.x);
    atomicAdd(&out[col + 1], acc.y);
    atomicAdd(&out[col + 2], acc.z);
    atomicAdd(&out[col + 3], acc.w);
}

// ---------------------------------------------------------------------------
// Final head: out[j] = bf[j] + sum_{i<8256} [result;meta][i] * Wf[i][j]
// ---------------------------------------------------------------------------
__global__ void final_init(const float* __restrict__ bf, float* __restrict__ outp) {
    int j = threadIdx.x;
    if (j < OUT_) outp[j] = bf[j];
}

__global__ __launch_bounds__(256) void final_kernel(
        const float* __restrict__ result, const float* __restrict__ meta,
        const float* __restrict__ Wf, float* __restrict__ outp) {
    const int ROWS = 258;  // 32*258 = 8256
    int r0 = blockIdx.x * ROWS;
    float acc[OUT_];
    #pragma unroll
    for (int j = 0; j < OUT_; j++) acc[j] = 0.0f;
    for (int i = r0 + threadIdx.x; i < r0 + ROWS; i += 256) {
        float cv = (i < N_) ? result[i] : meta[i - N_];
        #pragma unroll
        for (int j = 0; j < OUT_; j++) acc[j] += cv * Wf[i * OUT_ + j];
    }
    __shared__ float red[OUT_][257];
    #pragma unroll
    for (int j = 0; j < OUT_; j++) red[j][threadIdx.x] = acc[j];
    __syncthreads();
    for (int s = 128; s > 0; s >>= 1) {
        if (threadIdx.x < s) {
            #pragma unroll
            for (int j = 0; j < OUT_; j++)
                red[j][threadIdx.x] += red[j][threadIdx.x + s];
        }
        __syncthreads();
    }
    if (threadIdx.x == 0) {
        #pragma unroll
        for (int j = 0; j < OUT_; j++) atomicAdd(&outp[j], red[j][0]);
    }
}

// ---------------------------------------------------------------------------
// launcher
// ---------------------------------------------------------------------------
extern "C" void kernel_launch(void* const* d_in, const int* in_sizes, int n_in,
                              void* d_out, int out_size, void* d_ws, size_t ws_size,
                              hipStream_t stream) {
    (void)in_sizes; (void)n_in; (void)out_size; (void)ws_size;

    const float* x1   = (const float*)d_in[0];
    const float* x2   = (const float*)d_in[1];
    const float* meta = (const float*)d_in[2];
    const float* W1 = (const float*)d_in[3];  const float* b1 = (const float*)d_in[4];
    const float* W2 = (const float*)d_in[5];  const float* b2 = (const float*)d_in[6];
    const float* W3 = (const float*)d_in[7];  const float* b3 = (const float*)d_in[8];
    const float* W4 = (const float*)d_in[9];  const float* b4 = (const float*)d_in[10];
    const float* Wi = (const float*)d_in[11]; const float* bi = (const float*)d_in[12];
    const float* Wf = (const float*)d_in[13]; const float* bf = (const float*)d_in[14];
    const int* ei1 = (const int*)d_in[15];
    const int* ei2 = (const int*)d_in[16];
    float* out = (float*)d_out;

    // workspace (floats); ws re-poisoned each call -> everything used is written
    float* ws = (float*)d_ws;
    float* w      = ws;              // [128]
    float* betas  = w + 128;         // [4]
    float* deg    = betas + 4;       // [2N]
    float* dis    = deg + 2 * N_;    // [2N]
    float* p      = dis + 2 * N_;    // [2N]
    float* q      = p + 2 * N_;      // [2N]
    float* concat = q + 2 * N_;      // [2N]
    float* result = concat + 2 * N_; // [N]

    const int NB2 = 2 * N_ / 256;  // 64
    const int EB2 = 2 * E_ / 256;  // 2048

    compute_w<<<1, 128, 0, stream>>>(W1, W2, W3, W4, b1, b2, b3, b4, w, betas);
    deg_fill<<<NB2, 256, 0, stream>>>(deg);
    deg_accum2<<<EB2, 256, 0, stream>>>(ei1, ei2, deg);
    dis_k<<<NB2, 256, 0, stream>>>(deg, dis);

    dim3 bg(N_ / 4, 2);
    branch_gemv<<<bg, 256, 0, stream>>>(x1, x2, w, dis, p, q);

    for (int it = 0; it < 4; it++) {
        spmv2<<<EB2, 256, 0, stream>>>(ei1, ei2, p, q);
        if (it < 3)
            post2<false><<<NB2, 256, 0, stream>>>(dis, p, q, betas, it, concat, bi, result);
        else
            post2<true><<<NB2, 256, 0, stream>>>(dis, p, q, betas, it, concat, bi, result);
    }

    dim3 gg(8, 128);
    gemv_big<<<gg, 256, 0, stream>>>(Wi, concat, result);

    final_init<<<1, 32, 0, stream>>>(bf, out);
    final_kernel<<<32, 256, 0, stream>>>(result, meta, Wf, out);
}